// Round 9
// baseline (522.997 us; speedup 1.0000x reference)
//
// v6 resubmission #2 (r8 failure matched the r5/r6 infra-flake signature;
// swizzle/GELU/launch-bounds re-audited, no fault vector found).
#include <hip/hip_runtime.h>
#include <math.h>

#define B_  64
#define Cc  128
#define L_  3136

typedef __bf16 b8v __attribute__((ext_vector_type(8)));
typedef __bf16 b4v __attribute__((ext_vector_type(4)));
typedef float  f4v __attribute__((ext_vector_type(4)));

__device__ __forceinline__ f4v mfma16(b8v a, b8v b, f4v c) {
    return __builtin_amdgcn_mfma_f32_16x16x32_bf16(a, b, c, 0, 0, 0);
}
__device__ __forceinline__ int region(int h, int w) {
    int a = (h < 49) ? 0 : ((h < 53) ? 1 : 2);
    int b = (w < 49) ? 0 : ((w < 53) ? 1 : 2);
    return a * 3 + b;
}
// XOR-swizzled LDS index for [64][128] bf16 tiles: row-group reads spread
// across all banks; XOR of elem bits 3-5 preserves b8v/b4v alignment.
__device__ __forceinline__ int swz(int row, int col) {
    return row * 128 + (col ^ ((row & 7) << 3));
}
// tanh-approx GELU: v*sigmoid(2c(v+0.044715v^3)); |err| ~3e-4 << tolerance.
__device__ __forceinline__ float gelu_f(float v) {
    float s = v * v;
    float u = v * (1.5957691216057308f + 0.07135481987f * s);
    return v / (1.f + __expf(-u));
}

// ws layout: bf16 weights [0,196608) elems; biasmask f32[4][4][64][64] at byte 393216
__global__ __launch_bounds__(256) void prep_kernel(
    const float* __restrict__ qkv_w, const float* __restrict__ proj_w,
    const float* __restrict__ fc1_w, const float* __restrict__ fc2_w,
    const float* __restrict__ rpb,
    __bf16* __restrict__ wsb, float* __restrict__ bm)
{
    int i = blockIdx.x * 256 + threadIdx.x;
    if      (i <  49152) wsb[i] = (__bf16)qkv_w[i];
    else if (i <  65536) wsb[i] = (__bf16)proj_w[i - 49152];
    else if (i < 131072) wsb[i] = (__bf16)fc1_w[i - 65536];
    else if (i < 196608) wsb[i] = (__bf16)fc2_w[i - 131072];
    else {
        int idx = i - 196608;  // ((wt*4+h)*64+ii)*64+jj
        int jj = idx & 63, ii = (idx >> 6) & 63, h = (idx >> 12) & 3, wt = idx >> 14;
        float v;
        if (jj >= 49)      v = -1e30f;
        else if (ii >= 49) v = 0.f;
        else {
            int ih = ii / 7, iw = ii - ih * 7, jh = jj / 7, jw = jj - jh * 7;
            v = rpb[((ih - jh + 6) * 13 + (iw - jw + 6)) * 4 + h];
            int WH = (wt & 2) ? 49 : 0, WW = (wt & 1) ? 49 : 0;
            if (region(WH + ih, WW + iw) != region(WH + jh, WW + jw)) v -= 100.f;
        }
        bm[idx] = v;
    }
}

// ---- kernel A v6: LN1 + SW-MSA + proj + residual ----
// XOR-swizzled a_s/K_s (stride 128): conflict-free row-group ds reads.
// LDS 51200 -> 3 blocks/CU.
__global__ __launch_bounds__(256, 3) void swin_kernel(
    const float* __restrict__ x,
    const float* __restrict__ g1, const float* __restrict__ b1,
    const float* __restrict__ qkv_b, const float* __restrict__ proj_b,
    const __bf16* __restrict__ wqkv, const __bf16* __restrict__ wproj,
    const float* __restrict__ bm,
    float* __restrict__ out)
{
    __shared__ __bf16 a_s[64 * 128];   // LN1 -> Q overlay -> P scratch -> O
    __shared__ __bf16 K_s[64 * 128];   // K rows (all heads)
    __shared__ __bf16 VT_s[128 * 72];  // V^T [d][token] (stride 72, unswizzled)

    const int tid = threadIdx.x, w = tid >> 6, lane = tid & 63;
    const int quad = lane >> 4, r16 = lane & 15;
    const int blk = blockIdx.x, b = blk >> 6, wi = blk & 63;
    const int wh = wi >> 3, ww = wi & 7;
    const int wt = ((wh == 7) ? 2 : 0) | ((ww == 7) ? 1 : 0);
    const float scale = 0.17677669529663687f;  // 1/sqrt(32)

    // ---- LN1: wave w -> rows w*16..+15; 16-lane group per row ----
    {
        f4v gg0 = *(const f4v*)(g1 + r16 * 8), gg1 = *(const f4v*)(g1 + r16 * 8 + 4);
        f4v bb0 = *(const f4v*)(b1 + r16 * 8), bb1 = *(const f4v*)(b1 + r16 * 8 + 4);
        #pragma unroll
        for (int it = 0; it < 4; it++) {
            int local = it * 4 + quad;
            int t = w * 16 + local;
            b8v o;
            #pragma unroll
            for (int e = 0; e < 8; e++) o[e] = (__bf16)0.f;
            if (t < 49) {   // group-uniform branch
                int th = t / 7, tw = t - th * 7;
                int sh = wh * 7 + th + 3; if (sh >= 56) sh -= 56;
                int sw = ww * 7 + tw + 3; if (sw >= 56) sw -= 56;
                const float* xp = x + (b * L_ + sh * 56 + sw) * Cc + r16 * 8;
                f4v x0 = *(const f4v*)(xp), x1 = *(const f4v*)(xp + 4);
                float s = 0.f, q = 0.f;
                #pragma unroll
                for (int e = 0; e < 4; e++) {
                    s += x0[e] + x1[e];
                    q += x0[e] * x0[e] + x1[e] * x1[e];
                }
                s += __shfl_xor(s, 1, 64); q += __shfl_xor(q, 1, 64);
                s += __shfl_xor(s, 2, 64); q += __shfl_xor(q, 2, 64);
                s += __shfl_xor(s, 4, 64); q += __shfl_xor(q, 4, 64);
                s += __shfl_xor(s, 8, 64); q += __shfl_xor(q, 8, 64);
                float mu = s * (1.f / 128.f);
                float rs = rsqrtf(q * (1.f / 128.f) - mu * mu + 1e-5f);
                #pragma unroll
                for (int e = 0; e < 4; e++) {
                    o[e]     = (__bf16)((x0[e] - mu) * rs * gg0[e] + bb0[e]);
                    o[4 + e] = (__bf16)((x1[e] - mu) * rs * gg1[e] + bb1[e]);
                }
            }
            *(b8v*)(&a_s[swz(w * 16 + local, r16 * 8)]) = o;
        }
    }
    __syncthreads();

    // ---- cache A-fragments (all 64 rows) ----
    b8v A[4][4];
    #pragma unroll
    for (int mt = 0; mt < 4; mt++)
        #pragma unroll
        for (int i = 0; i < 4; i++)
            A[mt][i] = *(const b8v*)&a_s[swz(mt * 16 + r16, i * 32 + quad * 8)];
    __syncthreads();   // all waves done reading a_s; Q may overlay it

    // ---- QKV N-sliced: wave w -> cols w*96..+95; Q/K swapped, V unswapped ----
    #pragma unroll
    for (int nt6 = 0; nt6 < 6; nt6++) {
        const int col = w * 96 + nt6 * 16;    // wave-uniform
        const __bf16* bp = wqkv + (col + r16) * 128 + quad * 8;
        b8v B0 = *(const b8v*)(bp),      B1 = *(const b8v*)(bp + 32);
        b8v B2 = *(const b8v*)(bp + 64), B3 = *(const b8v*)(bp + 96);
        if (col < 256) {   // Q or K: D[qkcol][token], lane holds 4 contig cols
            f4v qb = *(const f4v*)(qkv_b + col + quad * 4);
            #pragma unroll
            for (int mt = 0; mt < 4; mt++) {
                f4v acc = {0.f, 0.f, 0.f, 0.f};
                acc = mfma16(B0, A[mt][0], acc);
                acc = mfma16(B1, A[mt][1], acc);
                acc = mfma16(B2, A[mt][2], acc);
                acc = mfma16(B3, A[mt][3], acc);
                b4v pk;
                if (col < 128) {
                    #pragma unroll
                    for (int r = 0; r < 4; r++) pk[r] = (__bf16)((acc[r] + qb[r]) * scale);
                    *(b4v*)&a_s[swz(mt * 16 + r16, col + quad * 4)] = pk;
                } else {
                    #pragma unroll
                    for (int r = 0; r < 4; r++) pk[r] = (__bf16)(acc[r] + qb[r]);
                    *(b4v*)&K_s[swz(mt * 16 + r16, (col - 128) + quad * 4)] = pk;
                }
            }
        } else {           // V: D[token][vcol]; 4 contig tokens -> VT rows
            float vb = qkv_b[col + r16];
            #pragma unroll
            for (int mt = 0; mt < 4; mt++) {
                f4v acc = {0.f, 0.f, 0.f, 0.f};
                acc = mfma16(A[mt][0], B0, acc);
                acc = mfma16(A[mt][1], B1, acc);
                acc = mfma16(A[mt][2], B2, acc);
                acc = mfma16(A[mt][3], B3, acc);
                b4v pk;
                #pragma unroll
                for (int r = 0; r < 4; r++) pk[r] = (__bf16)(acc[r] + vb);
                *(b4v*)(VT_s + (col - 256 + r16) * 72 + mt * 16 + quad * 4) = pk;
            }
        }
    }
    __syncthreads();

    // ---- preload own-strip Q for all heads (P scratch will overwrite it) ----
    b8v qf[4];
    #pragma unroll
    for (int h = 0; h < 4; h++)
        qf[h] = *(const b8v*)&a_s[swz(w * 16 + r16, h * 32 + quad * 8)];

    const float* bmq = bm + wt * 4 * 4096 + (w * 16 + r16) * 64;

    f4v o_acc[4][2];
    #pragma unroll
    for (int h = 0; h < 4; h++)
        #pragma unroll
        for (int n = 0; n < 2; n++)
            o_acc[h][n] = (f4v){0.f, 0.f, 0.f, 0.f};

    #pragma unroll
    for (int h = 0; h < 4; h++) {
        // S swapped: D[k][q]; lane r16 = own q-row, regs span 16 k
        f4v s[4];
        #pragma unroll
        for (int nt = 0; nt < 4; nt++) {
            b8v kf = *(const b8v*)&K_s[swz(nt * 16 + r16, h * 32 + quad * 8)];
            f4v z = {0.f, 0.f, 0.f, 0.f};
            s[nt] = mfma16(kf, qf[h], z);
        }
        // bias+mask (f4v) + exp (no max pass; pads are -1e30 -> exp==0)
        float sm = 0.f;
        #pragma unroll
        for (int nt = 0; nt < 4; nt++) {
            f4v mb = *(const f4v*)(bmq + h * 4096 + nt * 16 + quad * 4);
            #pragma unroll
            for (int r = 0; r < 4; r++) {
                s[nt][r] = __expf(s[nt][r] + mb[r]);
                sm += s[nt][r];
            }
        }
        sm += __shfl_xor(sm, 16, 64);
        sm += __shfl_xor(sm, 32, 64);
        float inv = 1.f / sm;
        // P -> wave-local rows of a_s (b4v, row = own q-row)
        #pragma unroll
        for (int nt = 0; nt < 4; nt++) {
            b4v pk;
            #pragma unroll
            for (int r = 0; r < 4; r++) pk[r] = (__bf16)(s[nt][r] * inv);
            *(b4v*)&a_s[swz(w * 16 + r16, nt * 16 + quad * 4)] = pk;
        }
        // PV swapped: D[d][q] accumulates in regs
        #pragma unroll
        for (int ks = 0; ks < 2; ks++) {
            b8v pf = *(const b8v*)&a_s[swz(w * 16 + r16, ks * 32 + quad * 8)];
            #pragma unroll
            for (int nt = 0; nt < 2; nt++) {
                b8v vf = *(const b8v*)(VT_s + (h * 32 + nt * 16 + r16) * 72 + ks * 32 + quad * 8);
                o_acc[h][nt] = mfma16(vf, pf, o_acc[h][nt]);
            }
        }
    }

    // ---- O -> own rows (b4v; lane r16 = own q-row, 4 contig d) ----
    #pragma unroll
    for (int h = 0; h < 4; h++)
        #pragma unroll
        for (int nt = 0; nt < 2; nt++) {
            b4v pk;
            #pragma unroll
            for (int r = 0; r < 4; r++) pk[r] = (__bf16)o_acc[h][nt][r];
            *(b4v*)&a_s[swz(w * 16 + r16, h * 32 + nt * 16 + quad * 4)] = pk;
        }
    __syncthreads();

    // ---- proj swapped + residual: f4v RMW, 4 contig out cols per lane ----
    {
        b8v O[4][4];
        #pragma unroll
        for (int mt = 0; mt < 4; mt++)
            #pragma unroll
            for (int i = 0; i < 4; i++)
                O[mt][i] = *(const b8v*)&a_s[swz(mt * 16 + r16, i * 32 + quad * 8)];

        #pragma unroll
        for (int nt = 0; nt < 2; nt++) {
            const int col = w * 32 + nt * 16;   // wave-uniform
            const __bf16* bp = wproj + (col + r16) * 128 + quad * 8;
            b8v B0 = *(const b8v*)(bp),      B1 = *(const b8v*)(bp + 32);
            b8v B2 = *(const b8v*)(bp + 64), B3 = *(const b8v*)(bp + 96);
            f4v pb = *(const f4v*)(proj_b + col + quad * 4);
            #pragma unroll
            for (int mt = 0; mt < 4; mt++) {
                f4v acc = {0.f, 0.f, 0.f, 0.f};
                acc = mfma16(B0, O[mt][0], acc);
                acc = mfma16(B1, O[mt][1], acc);
                acc = mfma16(B2, O[mt][2], acc);
                acc = mfma16(B3, O[mt][3], acc);
                int t = mt * 16 + r16;
                if (t < 49) {
                    int th = t / 7, tw = t - th * 7;
                    int sh = wh * 7 + th + 3; if (sh >= 56) sh -= 56;
                    int sw = ww * 7 + tw + 3; if (sw >= 56) sw -= 56;
                    int off = (b * L_ + sh * 56 + sw) * Cc + col + quad * 4;
                    f4v xr = *(const f4v*)(x + off);
                    f4v res;
                    #pragma unroll
                    for (int r = 0; r < 4; r++) res[r] = xr[r] + acc[r] + pb[r];
                    *(f4v*)(out + off) = res;
                }
            }
        }
    }
}

// ---- kernel B v5: LN2 + fc1 + GELU(tanh) + fc2 + residual ----
// XOR-swizzled x2/h1 (stride 128): LDS 32768 -> 5 blocks/CU.
__global__ __launch_bounds__(256, 5) void mlp_kernel(
    float* __restrict__ out,
    const float* __restrict__ g2, const float* __restrict__ b2,
    const __bf16* __restrict__ wfc1, const __bf16* __restrict__ wfc2,
    const float* __restrict__ fc1_b, const float* __restrict__ fc2_b)
{
    __shared__ __bf16 x2[64 * 128];   // LN2 out
    __shared__ __bf16 h1[64 * 128];   // hidden chunk (128 cols)

    const int tid = threadIdx.x, w = tid >> 6, lane = tid & 63;
    const int quad = lane >> 4, r16 = lane & 15;
    const int rowbase = blockIdx.x * 64;

    // ---- LN2: 4 threads per row (32 ch each) ----
    {
        const int r = tid >> 2, sub = tid & 3;
        const float* xp = out + (rowbase + r) * Cc + sub * 32;
        f4v xa[8];
        #pragma unroll
        for (int j = 0; j < 8; j++) xa[j] = *(const f4v*)(xp + j * 4);
        float s = 0.f, q = 0.f;
        #pragma unroll
        for (int j = 0; j < 8; j++)
            #pragma unroll
            for (int e = 0; e < 4; e++) { float v = xa[j][e]; s += v; q += v * v; }
        s += __shfl_xor(s, 1, 64); q += __shfl_xor(q, 1, 64);
        s += __shfl_xor(s, 2, 64); q += __shfl_xor(q, 2, 64);
        float mu = s * (1.f / 128.f);
        float rs = rsqrtf(q * (1.f / 128.f) - mu * mu + 1e-5f);
        #pragma unroll
        for (int j = 0; j < 8; j += 2) {
            int c = sub * 32 + j * 4;
            f4v gg0 = *(const f4v*)(g2 + c), gg1 = *(const f4v*)(g2 + c + 4);
            f4v bb0 = *(const f4v*)(b2 + c), bb1 = *(const f4v*)(b2 + c + 4);
            b8v o;
            #pragma unroll
            for (int e = 0; e < 4; e++) {
                o[e]     = (__bf16)((xa[j][e]     - mu) * rs * gg0[e] + bb0[e]);
                o[4 + e] = (__bf16)((xa[j + 1][e] - mu) * rs * gg1[e] + bb1[e]);
            }
            *(b8v*)(&x2[swz(r, c)]) = o;
        }
    }
    __syncthreads();

    f4v acc[4][2];   // fc2 accumulators: D[ocol][token]
    #pragma unroll
    for (int mt = 0; mt < 4; mt++)
        #pragma unroll
        for (int nt = 0; nt < 2; nt++)
            acc[mt][nt] = (f4v){0.f, 0.f, 0.f, 0.f};

    for (int hc = 0; hc < 4; hc++) {
        // ---- fc1 swapped + GELU: wave w -> hidden cols hc*128 + w*32..+31 ----
        {
            b8v Bf[2][4]; f4v b14[2];
            #pragma unroll
            for (int nt = 0; nt < 2; nt++) {
                const int col = hc * 128 + w * 32 + nt * 16;
                const __bf16* bp = wfc1 + (col + r16) * 128 + quad * 8;
                Bf[nt][0] = *(const b8v*)(bp);      Bf[nt][1] = *(const b8v*)(bp + 32);
                Bf[nt][2] = *(const b8v*)(bp + 64); Bf[nt][3] = *(const b8v*)(bp + 96);
                b14[nt] = *(const f4v*)(fc1_b + col + quad * 4);
            }
            #pragma unroll
            for (int mt = 0; mt < 4; mt++) {
                b8v A0 = *(const b8v*)&x2[swz(mt * 16 + r16, quad * 8)];
                b8v A1 = *(const b8v*)&x2[swz(mt * 16 + r16, quad * 8 + 32)];
                b8v A2 = *(const b8v*)&x2[swz(mt * 16 + r16, quad * 8 + 64)];
                b8v A3 = *(const b8v*)&x2[swz(mt * 16 + r16, quad * 8 + 96)];
                #pragma unroll
                for (int nt = 0; nt < 2; nt++) {
                    f4v a = {0.f, 0.f, 0.f, 0.f};
                    a = mfma16(Bf[nt][0], A0, a);
                    a = mfma16(Bf[nt][1], A1, a);
                    a = mfma16(Bf[nt][2], A2, a);
                    a = mfma16(Bf[nt][3], A3, a);
                    b4v pk;
                    #pragma unroll
                    for (int r = 0; r < 4; r++)
                        pk[r] = (__bf16)gelu_f(a[r] + b14[nt][r]);
                    *(b4v*)&h1[swz(mt * 16 + r16, w * 32 + nt * 16 + quad * 4)] = pk;
                }
            }
        }
        __syncthreads();
        // ---- fc2 partial (swapped): wave w -> out cols w*32..+31 ----
        #pragma unroll
        for (int Ks = 0; Ks < 4; Ks++) {
            b8v Af[4];
            #pragma unroll
            for (int mt = 0; mt < 4; mt++)
                Af[mt] = *(const b8v*)&h1[swz(mt * 16 + r16, Ks * 32 + quad * 8)];
            #pragma unroll
            for (int nt = 0; nt < 2; nt++) {
                const __bf16* bp = wfc2 + (w * 32 + nt * 16 + r16) * 512
                                 + hc * 128 + Ks * 32 + quad * 8;
                b8v Bf = *(const b8v*)(bp);
                #pragma unroll
                for (int mt = 0; mt < 4; mt++)
                    acc[mt][nt] = mfma16(Bf, Af[mt], acc[mt][nt]);
            }
        }
        if (hc < 3) __syncthreads();
    }

    // ---- epilogue: direct coalesced f4v residual RMW ----
    #pragma unroll
    for (int nt = 0; nt < 2; nt++) {
        const int col = w * 32 + nt * 16 + quad * 4;
        f4v fb = *(const f4v*)(fc2_b + col);
        #pragma unroll
        for (int mt = 0; mt < 4; mt++) {
            float* op = out + (rowbase + mt * 16 + r16) * Cc + col;
            f4v v = *(const f4v*)op;
            #pragma unroll
            for (int r = 0; r < 4; r++) v[r] += acc[mt][nt][r] + fb[r];
            *(f4v*)op = v;
        }
    }
}

extern "C" void kernel_launch(void* const* d_in, const int* in_sizes, int n_in,
                              void* d_out, int out_size, void* d_ws, size_t ws_size,
                              hipStream_t stream) {
    // 0 x, 1 ln1_g, 2 ln1_b, 3 qkv_w, 4 qkv_b, 5 rpb_table, 6 proj_w, 7 proj_b,
    // 8 ln2_g, 9 ln2_b, 10 fc1_w, 11 fc1_b, 12 fc2_w, 13 fc2_b
    __bf16* wsb = (__bf16*)d_ws;
    float*  bmp = (float*)((char*)d_ws + 393216);
    prep_kernel<<<1024, 256, 0, stream>>>(
        (const float*)d_in[3], (const float*)d_in[6],
        (const float*)d_in[10], (const float*)d_in[12],
        (const float*)d_in[5], wsb, bmp);
    swin_kernel<<<B_ * 64, 256, 0, stream>>>(
        (const float*)d_in[0],
        (const float*)d_in[1], (const float*)d_in[2],
        (const float*)d_in[4], (const float*)d_in[7],
        wsb, wsb + 49152,
        bmp, (float*)d_out);
    mlp_kernel<<<(B_ * L_) / 64, 256, 0, stream>>>(
        (float*)d_out,
        (const float*)d_in[8], (const float*)d_in[9],
        wsb + 65536, wsb + 131072,
        (const float*)d_in[11], (const float*)d_in[13]);
}